// Round 21
// baseline (521.113 us; speedup 1.0000x reference)
//
#include <hip/hip_runtime.h>
#include <hip/hip_bf16.h>

typedef unsigned short u16;
typedef unsigned char u8;
typedef unsigned long long u64;
typedef __attribute__((ext_vector_type(4))) int i32x4;
typedef __attribute__((ext_vector_type(8))) int i32x8;
typedef __attribute__((ext_vector_type(4))) float f32x4;

#define NROWS 4092      // 4 * 1023 valid token rows
#define NROWS_PAD 4096
#define DDIM 2048
#define VDIM 32768
#define NCHUNK 512      // 64-wide vocab chunks per row
#define SC8 0x7F7F7F7F  // e8m0 scale = 1.0 in all four bytes
#define BUFB 65536u     // LDS bytes per buffer: A 32K + B 32K

// ---------- helpers ----------
// RNE fp32 -> OCP e4m3fn (manual, incl. denormals + saturation to 448)
__device__ __forceinline__ u8 f2fp8(float f) {
  union { float f; unsigned u; } v; v.f = f;
  unsigned s = (v.u >> 24) & 0x80u;
  unsigned a = v.u & 0x7FFFFFFFu;
  if (a >= 0x43E80000u) return (u8)(s | 0x7E);   // |f| >= 464 -> 448
  int e = (int)(a >> 23) - 127;
  unsigned m = a & 0x7FFFFFu;
  if (e < -6) {                                   // denormal target
    unsigned full = m | 0x800000u;
    int sh = 20 + (-6 - e);
    if (sh > 31) return (u8)s;
    unsigned q = full >> sh;
    unsigned rem = full & ((1u << sh) - 1u), half = 1u << (sh - 1);
    q += (rem > half || (rem == half && (q & 1u)));
    return (u8)(s | q);
  }
  unsigned q = m >> 20, rem = m & 0xFFFFFu;
  q += (rem > 0x80000u || (rem == 0x80000u && (q & 1u)));
  unsigned bits = (((unsigned)(e + 7)) << 3) + q;
  if (bits >= 0x7Fu) bits = 0x7Eu;
  return (u8)(s | bits);
}

__device__ __forceinline__ void gload16(const void* g, void* l) {
  using gp_t = const __attribute__((address_space(1))) unsigned*;
  using lp_t = __attribute__((address_space(3))) unsigned*;
  __builtin_amdgcn_global_load_lds((gp_t)g, (lp_t)(unsigned)(unsigned long long)l,
                                   16, 0, 0);
}

#define BAR() __builtin_amdgcn_s_barrier()
#define SB()  __builtin_amdgcn_sched_barrier(0)
#define SHUF(a, b) __builtin_shufflevector(a, b, 0, 1, 2, 3, 4, 5, 6, 7)

// ---------- kernel 1: bucket chosen ids by 64-wide vocab tile -------------
__global__ void bucket_k(const int* __restrict__ ids,
                         int* __restrict__ boff, int* __restrict__ bent) {
  __shared__ int cnt[512];
  __shared__ int base[512];
  int tid = threadIdx.x;             // 512 threads
  cnt[tid] = 0;
  __syncthreads();
  int loc[8], tile[8], cid[8];
#pragma unroll
  for (int j = 0; j < 8; ++j) {
    int r = tid + (j << 9);
    int c = -1;
    if (r < NROWS) { int b = r / 1023, t = r % 1023; c = ids[b * 1024 + t + 1]; }
    cid[j] = c;
    int ti = (c < 0) ? 512 : (c >> 6);
    tile[j] = ti;
    loc[j] = (ti < 512) ? atomicAdd(&cnt[ti], 1) : 0;
  }
  __syncthreads();
  if (tid == 0) {
    int s = 0;
    for (int i = 0; i < 512; ++i) { base[i] = s; s += cnt[i]; }
  }
  __syncthreads();
  boff[tid] = base[tid];
  if (tid == 511) boff[512] = base[511] + cnt[511];
#pragma unroll
  for (int j = 0; j < 8; ++j) {
    int r = tid + (j << 9);
    if (tile[j] < 512) bent[base[tile[j]] + loc[j]] = (r << 6) | (cid[j] & 63);
  }
}

// ---------- kernel 2: h fp32 -> fp8 e4m3 (x16), row-remapped, padded ------
__global__ void conv_h(const float* __restrict__ hs, u8* __restrict__ h8,
                       float* __restrict__ chlog, float* __restrict__ accum) {
  int idx = blockIdx.x * 256 + threadIdx.x;   // 1,048,576 threads, 8 elems each
  if (idx < NROWS_PAD) chlog[idx] = 0.f;
  if (idx < 2) accum[idx] = 0.f;
  int row = idx >> 8;
  int c8 = (idx & 255) << 3;
  u64 o = 0;
  if (row < NROWS) {
    int b = row / 1023, t = row % 1023;
    const float* p = hs + (size_t)((b << 10) + t) * DDIM + c8;
    float4 x = *(const float4*)p, y = *(const float4*)(p + 4);
    o = (u64)f2fp8(x.x * 16.f)        | ((u64)f2fp8(x.y * 16.f) << 8) |
        ((u64)f2fp8(x.z * 16.f) << 16) | ((u64)f2fp8(x.w * 16.f) << 24) |
        ((u64)f2fp8(y.x * 16.f) << 32) | ((u64)f2fp8(y.y * 16.f) << 40) |
        ((u64)f2fp8(y.z * 16.f) << 48) | ((u64)f2fp8(y.w * 16.f) << 56);
  }
  *(u64*)(h8 + (size_t)row * DDIM + c8) = o;
}

// ---------- kernel 3: W (D x V fp32) -> W^T (V x D fp8 e4m3 x64)
// R14 body, 2-level block swizzle: within each 256-block group, 8 v-tiles x
// ALL 32 d-tiles are co-resident -> every 2048B WT8 row fills completely in
// L2 before eviction (full-line writeback, no partial-line thrash), while
// 8 consecutive v-blocks still stream 8x256B from each W row (read order).
__global__ void transpose_w(const float* __restrict__ W, u8* __restrict__ WT8,
                            const float* __restrict__ hs,
                            const int* __restrict__ boff,
                            const int* __restrict__ bent,
                            float* __restrict__ chlog) {
  __shared__ __align__(16) float t32[64][68];  // [d][v], row 272 B (16B-mult)
  __shared__ __align__(16) u8 t8[64][68];      // [d][v], u32-packed writes
  int bid = blockIdx.x;                        // 16384 blocks
  int grp = bid >> 8;                          // 64 groups of 256
  int r8 = bid & 255;
  int dt = r8 >> 3;                            // 0..31 (d-tile, mid-fast)
  int vt = (grp << 3) | (r8 & 7);              // v-tile: 8 per group (fastest)
  int v0 = vt << 6, d0 = dt << 6;
  int tid = threadIdx.x;
  int vi = (tid & 15) << 2, dl = tid >> 4;
#pragma unroll
  for (int i = 0; i < 4; ++i) {
    int d = dl + (i << 4);
    float4 w = *(const float4*)(W + (size_t)(d0 + d) * VDIM + v0 + vi);
    *(float4*)&t32[d][vi] = w;                  // 1x ds_write_b128
    unsigned p = (unsigned)f2fp8(w.x * 64.f) |
                 ((unsigned)f2fp8(w.y * 64.f) << 8) |
                 ((unsigned)f2fp8(w.z * 64.f) << 16) |
                 ((unsigned)f2fp8(w.w * 64.f) << 24);
    *(unsigned*)&t8[d][vi] = p;                 // 1x ds_write_b32
  }
  __syncthreads();
  // exact chosen dots first (atomics overlap with the output pass below)
  int m0 = boff[vt], m1 = boff[vt + 1];
  int lane = tid & 63, wv = tid >> 6;
  for (int m = m0 + wv; m < m1; m += 4) {
    int e = bent[m];
    int rr = e >> 6, cv = e & 63;
    int b = rr / 1023, tt = rr % 1023;
    float s = hs[(size_t)((b << 10) + tt) * DDIM + d0 + lane] * t32[lane][cv];
#pragma unroll
    for (int o = 1; o < 64; o <<= 1) s += __shfl_xor(s, o, 64);
    if (lane == 0) atomicAdd(chlog + rr, s);
  }
  // transposed fp8 write: 16 byte-reads (broadcast/2-way) + 16B global store
  int vr = tid >> 2, dc = (tid & 3) << 4;
  union { u8 b[16]; ulonglong2 q; } u;
#pragma unroll
  for (int k = 0; k < 16; ++k) u.b[k] = t8[dc + k][vr];
  *(ulonglong2*)(WT8 + (size_t)(v0 + vr) * DDIM + d0 + dc) = u.q;
}

// ---------- kernel 4: 256x256 fp8 GEMM, 128x64 wave tile, ni-outer loop ---
// (FROZEN: best measured 321 us, MfmaUtil 37.6%, 0 conflicts, no spill.)
__global__ __launch_bounds__(512, 2) void gemm_lse(
    const u8* __restrict__ A, const u8* __restrict__ Bt,
    float2* __restrict__ partials) {
  extern __shared__ u16 smem[];
  char* lds = (char*)smem;

  const int tid = threadIdx.x;
  const int l = tid & 63;
  const int wid = tid >> 6;                // 8 waves
  const int wm = wid >> 2, wn = wid & 3;   // 2 x 4
  const int ln = l & 15;
  const int g4 = l >> 4;
  const int xr = ln & 7;

  // XCD-bijective swizzle (2048 % 8 == 0)
  int bid = blockIdx.x;
  int id = ((bid & 7) << 8) | (bid >> 3);
  int bm = id & 15;                  // 0..15  (M tiles of 256)
  int bn = id >> 4;                  // 0..127 (N tiles of 256)
  const int m0 = bm << 8, n0 = bn << 8;

  const u8* Ab = A + (size_t)m0 * DDIM;
  const u8* Bb = Bt + (size_t)n0 * DDIM;

  // swizzled LDS read offsets: half u at slot ((u<<2)|g4) ^ xr, 16B units
  const unsigned aA0 = (unsigned)((wm << 14) + (ln << 7)) + (((0 | g4) ^ xr) << 4);
  const unsigned aA1 = (unsigned)((wm << 14) + (ln << 7)) + (((4 | g4) ^ xr) << 4);
  const unsigned aB0 = 32768u + (unsigned)((wn << 13) + (ln << 7)) + (((0 | g4) ^ xr) << 4);
  const unsigned aB1 = 32768u + (unsigned)((wn << 13) + (ln << 7)) + (((4 | g4) ^ xr) << 4);

  // staging: wave w stages segs {8j+w} j=0..3 (8 rows = 1 KB each) for A & B
  const int srow = l >> 3;
  const unsigned selb = (unsigned)(((l & 7) ^ srow) << 4);   // bytes
  unsigned voff[4];
#pragma unroll
  for (int j = 0; j < 4; ++j)
    voff[j] = (unsigned)(((((j << 3) + wid) << 3) | srow) * 2048) + selb;

#define RFL(x) __builtin_amdgcn_readfirstlane((int)(x))
#define GLL(src, dst) gload16((src), lds + RFL(dst))
#define LD4(off) (*(const i32x4*)(lds + (off)))
#define FRAG(b0, b1, o) SHUF(LD4((b0) + (o)), LD4((b1) + (o)))
#define DSTA(j) (unsigned)((((j) << 3) + wid) << 10)
#define DSTB(j) (32768u + (unsigned)((((j) << 3) + wid) << 10))

  f32x4 acc[8][4] = {};

  // prologue: tile0 (A+B) -> buf0; drain; barrier
#pragma unroll
  for (int j = 0; j < 4; ++j) GLL(Ab + voff[j], DSTA(j));
#pragma unroll
  for (int j = 0; j < 4; ++j) GLL(Bb + voff[j], DSTB(j));
  asm volatile("s_waitcnt vmcnt(0)" ::: "memory"); SB();
  BAR();
  SB();

  for (int t = 0; t < 16; ++t) {
    const unsigned fb = (unsigned)(t & 1) * BUFB;    // current buf
    const unsigned fbn = BUFB - fb;                  // next buf
    const u8* baseA = Ab + ((t + 1) << 7);           // A(t+1), uniform
    const u8* baseB = Bb + ((t + 1) << 7);           // B(t+1), uniform

    // FRONT-LOADED staging of tile t+1 (other buffer; no dependencies)
    if (t < 15) {
      GLL(baseA + voff[0], fbn + DSTA(0)); GLL(baseA + voff[1], fbn + DSTA(1));
      GLL(baseA + voff[2], fbn + DSTA(2)); GLL(baseA + voff[3], fbn + DSTA(3));
      GLL(baseB + voff[0], fbn + DSTB(0)); GLL(baseB + voff[1], fbn + DSTB(1));
      GLL(baseB + voff[2], fbn + DSTB(2)); GLL(baseB + voff[3], fbn + DSTB(3));
    }

    const unsigned rA0 = fb + aA0, rA1 = fb + aA1;
    const unsigned rB0 = fb + aB0, rB1 = fb + aB1;

    // A operands for the whole tile: af[8] = 64 regs (16 ds_read_b128)
    i32x8 af[8];
#pragma unroll
    for (int mi = 0; mi < 8; ++mi) af[mi] = FRAG(rA0, rA1, mi * 2048);

#pragma unroll
    for (int ni = 0; ni < 4; ++ni) {
      i32x8 bf = FRAG(rB0, rB1, ni * 2048);
#pragma unroll
      for (int mi = 0; mi < 8; ++mi)
        acc[mi][ni] = __builtin_amdgcn_mfma_scale_f32_16x16x128_f8f6f4(
            af[mi], bf, acc[mi][ni], 0, 0, 0, SC8, 0, SC8);
    }
    if (t < 15) { asm volatile("s_waitcnt vmcnt(0)" ::: "memory"); }
    SB();
    BAR();   // boundary: tile t+1 fully landed, flip buffer
    SB();
  }

  // epilogue: per-row (max, sum-exp) over the wave's 64 cols (scale /1024)
  // C/D layout: col = lane&15, row = (lane>>4)*4 + reg
  const int chunk = (bn << 2) | wn;
#pragma unroll
  for (int mi = 0; mi < 8; ++mi) {
#pragma unroll
    for (int rr = 0; rr < 4; ++rr) {
      const int row = m0 + (wm << 7) + (mi << 4) + (g4 << 2) + rr;
      float v0 = acc[mi][0][rr] * 0.0009765625f;
      float v1 = acc[mi][1][rr] * 0.0009765625f;
      float v2 = acc[mi][2][rr] * 0.0009765625f;
      float v3 = acc[mi][3][rr] * 0.0009765625f;
      float mx = fmaxf(fmaxf(v0, v1), fmaxf(v2, v3));
#pragma unroll
      for (int o = 1; o < 16; o <<= 1) mx = fmaxf(mx, __shfl_xor(mx, o, 64));
      float s = __expf(v0 - mx) + __expf(v1 - mx) + __expf(v2 - mx) + __expf(v3 - mx);
#pragma unroll
      for (int o = 1; o < 16; o <<= 1) s += __shfl_xor(s, o, 64);
      if (ln == 0) partials[(size_t)row * NCHUNK + chunk] = make_float2(mx, s);
    }
  }
#undef DSTA
#undef DSTB
#undef FRAG
#undef LD4
#undef GLL
#undef RFL
}

// ---------- kernel 5: combine partials -> lse -> logps -> loss terms ----------
__global__ void reduce_lse(const float2* __restrict__ partials,
                           const float* __restrict__ chlog,
                           const float* __restrict__ oldlp,
                           const int* __restrict__ labels,
                           const float* __restrict__ adv,
                           float* __restrict__ out, float* __restrict__ accum) {
  const int wid = threadIdx.x >> 6, l = threadIdx.x & 63;
  const int row = blockIdx.x * 4 + wid;        // 1023*4 = 4092 exactly
  float M = -INFINITY, S = 0.f;
  for (int c = l; c < NCHUNK; c += 64) {
    float2 p = partials[(size_t)row * NCHUNK + c];
    float Mn = fmaxf(M, p.x);
    S = S * __expf(M - Mn) + p.y * __expf(p.x - Mn);
    M = Mn;
  }
#pragma unroll
  for (int o = 1; o < 64; o <<= 1) {
    float Mo = __shfl_xor(M, o, 64), So = __shfl_xor(S, o, 64);
    float Mn = fmaxf(M, Mo);
    S = S * __expf(M - Mn) + So * __expf(Mo - Mn);
    M = Mn;
  }
  if (l == 0) {
    float lse = M + __logf(S);
    float ptl = chlog[row] - lse;
    out[1 + row] = ptl;
    int b = row / 1023, t = row % 1023;
    float a = adv[b];
    float ratio = __expf(ptl - oldlp[row]);
    float l1 = ratio * a;
    float l2 = fminf(fmaxf(ratio, 0.8f), 1.3f) * a;
    float mk = (float)labels[b * 1024 + t + 1];
    atomicAdd(accum + 0, -fminf(l1, l2) * mk);
    atomicAdd(accum + 1, mk);
  }
}

__global__ void finalize_k(const float* __restrict__ accum, float* __restrict__ out) {
  out[0] = accum[0] / accum[1];
}

// ---------- launch ----------
extern "C" void kernel_launch(void* const* d_in, const int* in_sizes, int n_in,
                              void* d_out, int out_size, void* d_ws, size_t ws_size,
                              hipStream_t stream) {
  const float* hs     = (const float*)d_in[0];   // (4,1024,2048)
  const float* W      = (const float*)d_in[1];   // (2048,32768)
  const int*   ids    = (const int*)d_in[2];     // (4,1024)
  const int*   labels = (const int*)d_in[3];     // (4,1024)
  const float* adv    = (const float*)d_in[4];   // (4,)
  const float* oldlp  = (const float*)d_in[5];   // (4,1023)
  float* out = (float*)d_out;                    // [loss, 4092 x per_token_logps]

  // ws layout (~92.4 MB)
  char* ws = (char*)d_ws;
  u8*     WT8      = (u8*)ws;                          //  67,108,864 B
  u8*     h8       = (u8*)(ws + 67108864);             //   8,388,608 B
  float2* partials = (float2*)(ws + 75497472);         //  16,777,216 B
  float*  chlog    = (float*)(ws + 92274688);          //      16,384 B
  float*  accum    = (float*)(ws + 92291072);          //          64 B (pad)
  int*    boff     = (int*)(ws + 92291136);            //       2,112 B (513+pad)
  int*    bent     = (int*)(ws + 92293248);            //      16,384 B

  (void)hipFuncSetAttribute((const void*)gemm_lse,
                            hipFuncAttributeMaxDynamicSharedMemorySize, 131072);

  bucket_k<<<1, 512, 0, stream>>>(ids, boff, bent);
  conv_h<<<4096, 256, 0, stream>>>(hs, h8, chlog, accum);
  transpose_w<<<16384, 256, 0, stream>>>(W, WT8, hs, boff, bent, chlog);
  gemm_lse<<<2048, 512, 131072, stream>>>(h8, WT8, partials);
  reduce_lse<<<1023, 256, 0, stream>>>(partials, chlog, oldlp, labels, adv, out, accum);
  finalize_k<<<1, 1, 0, stream>>>(accum, out);
}

// Round 22
// 503.593 us; speedup vs baseline: 1.0348x; 1.0348x over previous
//
#include <hip/hip_runtime.h>
#include <hip/hip_bf16.h>

typedef unsigned short u16;
typedef unsigned char u8;
typedef unsigned long long u64;
typedef __attribute__((ext_vector_type(4))) int i32x4;
typedef __attribute__((ext_vector_type(8))) int i32x8;
typedef __attribute__((ext_vector_type(4))) float f32x4;

#define NROWS 4092      // 4 * 1023 valid token rows
#define NROWS_PAD 4096
#define DDIM 2048
#define VDIM 32768
#define NCHUNK 512      // 64-wide vocab chunks per row
#define SC8 0x7F7F7F7F  // e8m0 scale = 1.0 in all four bytes
#define BUFB 65536u     // LDS bytes per buffer: A 32K + B 32K

// ---------- helpers ----------
// RNE fp32 -> OCP e4m3fn (manual, incl. denormals + saturation to 448)
__device__ __forceinline__ u8 f2fp8(float f) {
  union { float f; unsigned u; } v; v.f = f;
  unsigned s = (v.u >> 24) & 0x80u;
  unsigned a = v.u & 0x7FFFFFFFu;
  if (a >= 0x43E80000u) return (u8)(s | 0x7E);   // |f| >= 464 -> 448
  int e = (int)(a >> 23) - 127;
  unsigned m = a & 0x7FFFFFu;
  if (e < -6) {                                   // denormal target
    unsigned full = m | 0x800000u;
    int sh = 20 + (-6 - e);
    if (sh > 31) return (u8)s;
    unsigned q = full >> sh;
    unsigned rem = full & ((1u << sh) - 1u), half = 1u << (sh - 1);
    q += (rem > half || (rem == half && (q & 1u)));
    return (u8)(s | q);
  }
  unsigned q = m >> 20, rem = m & 0xFFFFFu;
  q += (rem > 0x80000u || (rem == 0x80000u && (q & 1u)));
  unsigned bits = (((unsigned)(e + 7)) << 3) + q;
  if (bits >= 0x7Fu) bits = 0x7Eu;
  return (u8)(s | bits);
}

__device__ __forceinline__ void gload16(const void* g, void* l) {
  using gp_t = const __attribute__((address_space(1))) unsigned*;
  using lp_t = __attribute__((address_space(3))) unsigned*;
  __builtin_amdgcn_global_load_lds((gp_t)g, (lp_t)(unsigned)(unsigned long long)l,
                                   16, 0, 0);
}

#define BAR() __builtin_amdgcn_s_barrier()
#define SB()  __builtin_amdgcn_sched_barrier(0)
#define SHUF(a, b) __builtin_shufflevector(a, b, 0, 1, 2, 3, 4, 5, 6, 7)

// ---------- kernel 1: bucket chosen ids by 64-wide vocab tile -------------
__global__ void bucket_k(const int* __restrict__ ids,
                         int* __restrict__ boff, int* __restrict__ bent) {
  __shared__ int cnt[512];
  __shared__ int base[512];
  int tid = threadIdx.x;             // 512 threads
  cnt[tid] = 0;
  __syncthreads();
  int loc[8], tile[8], cid[8];
#pragma unroll
  for (int j = 0; j < 8; ++j) {
    int r = tid + (j << 9);
    int c = -1;
    if (r < NROWS) { int b = r / 1023, t = r % 1023; c = ids[b * 1024 + t + 1]; }
    cid[j] = c;
    int ti = (c < 0) ? 512 : (c >> 6);
    tile[j] = ti;
    loc[j] = (ti < 512) ? atomicAdd(&cnt[ti], 1) : 0;
  }
  __syncthreads();
  if (tid == 0) {
    int s = 0;
    for (int i = 0; i < 512; ++i) { base[i] = s; s += cnt[i]; }
  }
  __syncthreads();
  boff[tid] = base[tid];
  if (tid == 511) boff[512] = base[511] + cnt[511];
#pragma unroll
  for (int j = 0; j < 8; ++j) {
    int r = tid + (j << 9);
    if (tile[j] < 512) bent[base[tile[j]] + loc[j]] = (r << 6) | (cid[j] & 63);
  }
}

// ---------- kernel 2: h fp32 -> fp8 e4m3 (x16), row-remapped, padded ------
__global__ void conv_h(const float* __restrict__ hs, u8* __restrict__ h8,
                       float* __restrict__ chlog, float* __restrict__ accum) {
  int idx = blockIdx.x * 256 + threadIdx.x;   // 1,048,576 threads, 8 elems each
  if (idx < NROWS_PAD) chlog[idx] = 0.f;
  if (idx < 2) accum[idx] = 0.f;
  int row = idx >> 8;
  int c8 = (idx & 255) << 3;
  u64 o = 0;
  if (row < NROWS) {
    int b = row / 1023, t = row % 1023;
    const float* p = hs + (size_t)((b << 10) + t) * DDIM + c8;
    float4 x = *(const float4*)p, y = *(const float4*)(p + 4);
    o = (u64)f2fp8(x.x * 16.f)        | ((u64)f2fp8(x.y * 16.f) << 8) |
        ((u64)f2fp8(x.z * 16.f) << 16) | ((u64)f2fp8(x.w * 16.f) << 24) |
        ((u64)f2fp8(y.x * 16.f) << 32) | ((u64)f2fp8(y.y * 16.f) << 40) |
        ((u64)f2fp8(y.z * 16.f) << 48) | ((u64)f2fp8(y.w * 16.f) << 56);
  }
  *(u64*)(h8 + (size_t)row * DDIM + c8) = o;
}

// ---------- kernel 3: W (D x V fp32) -> W^T (V x D fp8 e4m3 x64)
//            + EXACT fp32 chosen-logit partial dots (R14/R20 form, best) ----
__global__ void transpose_w(const float* __restrict__ W, u8* __restrict__ WT8,
                            const float* __restrict__ hs,
                            const int* __restrict__ boff,
                            const int* __restrict__ bent,
                            float* __restrict__ chlog) {
  __shared__ __align__(16) float t32[64][68];  // [d][v], row 272 B (16B-mult)
  __shared__ __align__(16) u8 t8[64][68];      // [d][v], u32-packed writes
  int v0 = blockIdx.x << 6, d0 = blockIdx.y << 6;
  int tid = threadIdx.x;
  int vi = (tid & 15) << 2, dl = tid >> 4;
#pragma unroll
  for (int i = 0; i < 4; ++i) {
    int d = dl + (i << 4);
    float4 w = *(const float4*)(W + (size_t)(d0 + d) * VDIM + v0 + vi);
    *(float4*)&t32[d][vi] = w;                  // 1x ds_write_b128
    unsigned p = (unsigned)f2fp8(w.x * 64.f) |
                 ((unsigned)f2fp8(w.y * 64.f) << 8) |
                 ((unsigned)f2fp8(w.z * 64.f) << 16) |
                 ((unsigned)f2fp8(w.w * 64.f) << 24);
    *(unsigned*)&t8[d][vi] = p;                 // 1x ds_write_b32
  }
  __syncthreads();
  // exact chosen dots first (atomics overlap with the output pass below)
  int m0 = boff[blockIdx.x], m1 = boff[blockIdx.x + 1];
  int lane = tid & 63, wv = tid >> 6;
  for (int m = m0 + wv; m < m1; m += 4) {
    int e = bent[m];
    int r = e >> 6, cv = e & 63;
    int b = r / 1023, tt = r % 1023;
    float s = hs[(size_t)((b << 10) + tt) * DDIM + d0 + lane] * t32[lane][cv];
#pragma unroll
    for (int o = 1; o < 64; o <<= 1) s += __shfl_xor(s, o, 64);
    if (lane == 0) atomicAdd(chlog + r, s);
  }
  // transposed fp8 write: 16 byte-reads (broadcast/2-way) + 16B global store
  int vr = tid >> 2, dc = (tid & 3) << 4;
  union { u8 b[16]; ulonglong2 q; } u;
#pragma unroll
  for (int k = 0; k < 16; ++k) u.b[k] = t8[dc + k][vr];
  *(ulonglong2*)(WT8 + (size_t)(v0 + vr) * DDIM + d0 + dc) = u.q;
}

// ---------- kernel 4: 256x256 fp8 GEMM, 128x64 wave tile, ni-outer loop ---
// (FROZEN: best measured 321 us, MfmaUtil 37.6%, 0 conflicts, no spill.)
__global__ __launch_bounds__(512, 2) void gemm_lse(
    const u8* __restrict__ A, const u8* __restrict__ Bt,
    float2* __restrict__ partials) {
  extern __shared__ u16 smem[];
  char* lds = (char*)smem;

  const int tid = threadIdx.x;
  const int l = tid & 63;
  const int wid = tid >> 6;                // 8 waves
  const int wm = wid >> 2, wn = wid & 3;   // 2 x 4
  const int ln = l & 15;
  const int g4 = l >> 4;
  const int xr = ln & 7;

  // XCD-bijective swizzle (2048 % 8 == 0)
  int bid = blockIdx.x;
  int id = ((bid & 7) << 8) | (bid >> 3);
  int bm = id & 15;                  // 0..15  (M tiles of 256)
  int bn = id >> 4;                  // 0..127 (N tiles of 256)
  const int m0 = bm << 8, n0 = bn << 8;

  const u8* Ab = A + (size_t)m0 * DDIM;
  const u8* Bb = Bt + (size_t)n0 * DDIM;

  // swizzled LDS read offsets: half u at slot ((u<<2)|g4) ^ xr, 16B units
  const unsigned aA0 = (unsigned)((wm << 14) + (ln << 7)) + (((0 | g4) ^ xr) << 4);
  const unsigned aA1 = (unsigned)((wm << 14) + (ln << 7)) + (((4 | g4) ^ xr) << 4);
  const unsigned aB0 = 32768u + (unsigned)((wn << 13) + (ln << 7)) + (((0 | g4) ^ xr) << 4);
  const unsigned aB1 = 32768u + (unsigned)((wn << 13) + (ln << 7)) + (((4 | g4) ^ xr) << 4);

  // staging: wave w stages segs {8j+w} j=0..3 (8 rows = 1 KB each) for A & B
  const int srow = l >> 3;
  const unsigned selb = (unsigned)(((l & 7) ^ srow) << 4);   // bytes
  unsigned voff[4];
#pragma unroll
  for (int j = 0; j < 4; ++j)
    voff[j] = (unsigned)(((((j << 3) + wid) << 3) | srow) * 2048) + selb;

#define RFL(x) __builtin_amdgcn_readfirstlane((int)(x))
#define GLL(src, dst) gload16((src), lds + RFL(dst))
#define LD4(off) (*(const i32x4*)(lds + (off)))
#define FRAG(b0, b1, o) SHUF(LD4((b0) + (o)), LD4((b1) + (o)))
#define DSTA(j) (unsigned)((((j) << 3) + wid) << 10)
#define DSTB(j) (32768u + (unsigned)((((j) << 3) + wid) << 10))

  f32x4 acc[8][4] = {};

  // prologue: tile0 (A+B) -> buf0; drain; barrier
#pragma unroll
  for (int j = 0; j < 4; ++j) GLL(Ab + voff[j], DSTA(j));
#pragma unroll
  for (int j = 0; j < 4; ++j) GLL(Bb + voff[j], DSTB(j));
  asm volatile("s_waitcnt vmcnt(0)" ::: "memory"); SB();
  BAR();
  SB();

  for (int t = 0; t < 16; ++t) {
    const unsigned fb = (unsigned)(t & 1) * BUFB;    // current buf
    const unsigned fbn = BUFB - fb;                  // next buf
    const u8* baseA = Ab + ((t + 1) << 7);           // A(t+1), uniform
    const u8* baseB = Bb + ((t + 1) << 7);           // B(t+1), uniform

    // FRONT-LOADED staging of tile t+1 (other buffer; no dependencies)
    if (t < 15) {
      GLL(baseA + voff[0], fbn + DSTA(0)); GLL(baseA + voff[1], fbn + DSTA(1));
      GLL(baseA + voff[2], fbn + DSTA(2)); GLL(baseA + voff[3], fbn + DSTA(3));
      GLL(baseB + voff[0], fbn + DSTB(0)); GLL(baseB + voff[1], fbn + DSTB(1));
      GLL(baseB + voff[2], fbn + DSTB(2)); GLL(baseB + voff[3], fbn + DSTB(3));
    }

    const unsigned rA0 = fb + aA0, rA1 = fb + aA1;
    const unsigned rB0 = fb + aB0, rB1 = fb + aB1;

    // A operands for the whole tile: af[8] = 64 regs (16 ds_read_b128)
    i32x8 af[8];
#pragma unroll
    for (int mi = 0; mi < 8; ++mi) af[mi] = FRAG(rA0, rA1, mi * 2048);

#pragma unroll
    for (int ni = 0; ni < 4; ++ni) {
      i32x8 bf = FRAG(rB0, rB1, ni * 2048);
#pragma unroll
      for (int mi = 0; mi < 8; ++mi)
        acc[mi][ni] = __builtin_amdgcn_mfma_scale_f32_16x16x128_f8f6f4(
            af[mi], bf, acc[mi][ni], 0, 0, 0, SC8, 0, SC8);
    }
    if (t < 15) { asm volatile("s_waitcnt vmcnt(0)" ::: "memory"); }
    SB();
    BAR();   // boundary: tile t+1 fully landed, flip buffer
    SB();
  }

  // epilogue: per-row (max, sum-exp) over the wave's 64 cols (scale /1024)
  // C/D layout: col = lane&15, row = (lane>>4)*4 + reg
  const int chunk = (bn << 2) | wn;
#pragma unroll
  for (int mi = 0; mi < 8; ++mi) {
#pragma unroll
    for (int rr = 0; rr < 4; ++rr) {
      const int row = m0 + (wm << 7) + (mi << 4) + (g4 << 2) + rr;
      float v0 = acc[mi][0][rr] * 0.0009765625f;
      float v1 = acc[mi][1][rr] * 0.0009765625f;
      float v2 = acc[mi][2][rr] * 0.0009765625f;
      float v3 = acc[mi][3][rr] * 0.0009765625f;
      float mx = fmaxf(fmaxf(v0, v1), fmaxf(v2, v3));
#pragma unroll
      for (int o = 1; o < 16; o <<= 1) mx = fmaxf(mx, __shfl_xor(mx, o, 64));
      float s = __expf(v0 - mx) + __expf(v1 - mx) + __expf(v2 - mx) + __expf(v3 - mx);
#pragma unroll
      for (int o = 1; o < 16; o <<= 1) s += __shfl_xor(s, o, 64);
      if (ln == 0) partials[(size_t)row * NCHUNK + chunk] = make_float2(mx, s);
    }
  }
#undef DSTA
#undef DSTB
#undef FRAG
#undef LD4
#undef GLL
#undef RFL
}

// ---------- kernel 5: combine partials -> lse -> logps -> loss terms ----------
__global__ void reduce_lse(const float2* __restrict__ partials,
                           const float* __restrict__ chlog,
                           const float* __restrict__ oldlp,
                           const int* __restrict__ labels,
                           const float* __restrict__ adv,
                           float* __restrict__ out, float* __restrict__ accum) {
  const int wid = threadIdx.x >> 6, l = threadIdx.x & 63;
  const int row = blockIdx.x * 4 + wid;        // 1023*4 = 4092 exactly
  float M = -INFINITY, S = 0.f;
  for (int c = l; c < NCHUNK; c += 64) {
    float2 p = partials[(size_t)row * NCHUNK + c];
    float Mn = fmaxf(M, p.x);
    S = S * __expf(M - Mn) + p.y * __expf(p.x - Mn);
    M = Mn;
  }
#pragma unroll
  for (int o = 1; o < 64; o <<= 1) {
    float Mo = __shfl_xor(M, o, 64), So = __shfl_xor(S, o, 64);
    float Mn = fmaxf(M, Mo);
    S = S * __expf(M - Mn) + So * __expf(Mo - Mn);
    M = Mn;
  }
  if (l == 0) {
    float lse = M + __logf(S);
    float ptl = chlog[row] - lse;
    out[1 + row] = ptl;
    int b = row / 1023, t = row % 1023;
    float a = adv[b];
    float ratio = __expf(ptl - oldlp[row]);
    float l1 = ratio * a;
    float l2 = fminf(fmaxf(ratio, 0.8f), 1.3f) * a;
    float mk = (float)labels[b * 1024 + t + 1];
    atomicAdd(accum + 0, -fminf(l1, l2) * mk);
    atomicAdd(accum + 1, mk);
  }
}

__global__ void finalize_k(const float* __restrict__ accum, float* __restrict__ out) {
  out[0] = accum[0] / accum[1];
}

// ---------- launch ----------
extern "C" void kernel_launch(void* const* d_in, const int* in_sizes, int n_in,
                              void* d_out, int out_size, void* d_ws, size_t ws_size,
                              hipStream_t stream) {
  const float* hs     = (const float*)d_in[0];   // (4,1024,2048)
  const float* W      = (const float*)d_in[1];   // (2048,32768)
  const int*   ids    = (const int*)d_in[2];     // (4,1024)
  const int*   labels = (const int*)d_in[3];     // (4,1024)
  const float* adv    = (const float*)d_in[4];   // (4,)
  const float* oldlp  = (const float*)d_in[5];   // (4,1023)
  float* out = (float*)d_out;                    // [loss, 4092 x per_token_logps]

  // ws layout (~92.4 MB)
  char* ws = (char*)d_ws;
  u8*     WT8      = (u8*)ws;                          //  67,108,864 B
  u8*     h8       = (u8*)(ws + 67108864);             //   8,388,608 B
  float2* partials = (float2*)(ws + 75497472);         //  16,777,216 B
  float*  chlog    = (float*)(ws + 92274688);          //      16,384 B
  float*  accum    = (float*)(ws + 92291072);          //          64 B (pad)
  int*    boff     = (int*)(ws + 92291136);            //       2,112 B (513+pad)
  int*    bent     = (int*)(ws + 92293248);            //      16,384 B

  (void)hipFuncSetAttribute((const void*)gemm_lse,
                            hipFuncAttributeMaxDynamicSharedMemorySize, 131072);

  bucket_k<<<1, 512, 0, stream>>>(ids, boff, bent);
  conv_h<<<4096, 256, 0, stream>>>(hs, h8, chlog, accum);
  transpose_w<<<dim3(512, 32), 256, 0, stream>>>(W, WT8, hs, boff, bent, chlog);
  gemm_lse<<<2048, 512, 131072, stream>>>(h8, WT8, partials);
  reduce_lse<<<1023, 256, 0, stream>>>(partials, chlog, oldlp, labels, adv, out, accum);
  finalize_k<<<1, 1, 0, stream>>>(accum, out);
}

// Round 23
// 493.963 us; speedup vs baseline: 1.0550x; 1.0195x over previous
//
#include <hip/hip_runtime.h>
#include <hip/hip_bf16.h>

typedef unsigned short u16;
typedef unsigned char u8;
typedef unsigned long long u64;
typedef __attribute__((ext_vector_type(4))) int i32x4;
typedef __attribute__((ext_vector_type(8))) int i32x8;
typedef __attribute__((ext_vector_type(4))) float f32x4;

#define NROWS 4092      // 4 * 1023 valid token rows
#define NROWS_PAD 4096
#define DDIM 2048
#define VDIM 32768
#define NCHUNK 512      // 64-wide vocab chunks per row
#define SC8 0x7F7F7F7F  // e8m0 scale = 1.0 in all four bytes
#define BUFB 65536u     // LDS bytes per buffer: A 32K + B 32K

// ---------- helpers ----------
// RNE fp32 -> OCP e4m3fn (manual, incl. denormals + saturation to 448)
__device__ __forceinline__ u8 f2fp8(float f) {
  union { float f; unsigned u; } v; v.f = f;
  unsigned s = (v.u >> 24) & 0x80u;
  unsigned a = v.u & 0x7FFFFFFFu;
  if (a >= 0x43E80000u) return (u8)(s | 0x7E);   // |f| >= 464 -> 448
  int e = (int)(a >> 23) - 127;
  unsigned m = a & 0x7FFFFFu;
  if (e < -6) {                                   // denormal target
    unsigned full = m | 0x800000u;
    int sh = 20 + (-6 - e);
    if (sh > 31) return (u8)s;
    unsigned q = full >> sh;
    unsigned rem = full & ((1u << sh) - 1u), half = 1u << (sh - 1);
    q += (rem > half || (rem == half && (q & 1u)));
    return (u8)(s | q);
  }
  unsigned q = m >> 20, rem = m & 0xFFFFFu;
  q += (rem > 0x80000u || (rem == 0x80000u && (q & 1u)));
  unsigned bits = (((unsigned)(e + 7)) << 3) + q;
  if (bits >= 0x7Fu) bits = 0x7Eu;
  return (u8)(s | bits);
}

__device__ __forceinline__ void gload16(const void* g, void* l) {
  using gp_t = const __attribute__((address_space(1))) unsigned*;
  using lp_t = __attribute__((address_space(3))) unsigned*;
  __builtin_amdgcn_global_load_lds((gp_t)g, (lp_t)(unsigned)(unsigned long long)l,
                                   16, 0, 0);
}

#define BAR() __builtin_amdgcn_s_barrier()
#define SB()  __builtin_amdgcn_sched_barrier(0)
#define SHUF(a, b) __builtin_shufflevector(a, b, 0, 1, 2, 3, 4, 5, 6, 7)

// ---------- kernel 1: bucket chosen ids + zero chlog/accum ----------------
// (zeroing lives here so the merged conv/transpose kernel's atomics are safe)
__global__ void bucket_k(const int* __restrict__ ids,
                         int* __restrict__ boff, int* __restrict__ bent,
                         float* __restrict__ chlog, float* __restrict__ accum) {
  __shared__ int cnt[512];
  __shared__ int base[512];
  int tid = threadIdx.x;             // 512 threads
  cnt[tid] = 0;
  if (tid < 2) accum[tid] = 0.f;
#pragma unroll
  for (int j = 0; j < 8; ++j) chlog[tid + (j << 9)] = 0.f;
  __syncthreads();
  int loc[8], tile[8], cid[8];
#pragma unroll
  for (int j = 0; j < 8; ++j) {
    int r = tid + (j << 9);
    int c = -1;
    if (r < NROWS) { int b = r / 1023, t = r % 1023; c = ids[b * 1024 + t + 1]; }
    cid[j] = c;
    int ti = (c < 0) ? 512 : (c >> 6);
    tile[j] = ti;
    loc[j] = (ti < 512) ? atomicAdd(&cnt[ti], 1) : 0;
  }
  __syncthreads();
  if (tid == 0) {
    int s = 0;
    for (int i = 0; i < 512; ++i) { base[i] = s; s += cnt[i]; }
  }
  __syncthreads();
  boff[tid] = base[tid];
  if (tid == 511) boff[512] = base[511] + cnt[511];
#pragma unroll
  for (int j = 0; j < 8; ++j) {
    int r = tid + (j << 9);
    if (tile[j] < 512) bent[base[tile[j]] + loc[j]] = (r << 6) | (cid[j] & 63);
  }
}

// ---------- kernel 2: MERGED transpose_w + conv_h ------------------------
// Blocks < 16384: W (D x V fp32) -> W^T (V x D fp8 x64) + exact chosen dots
//   (vt = bid & 511, dt = bid >> 9 — same traversal as the old (512,32) grid)
// Blocks >= 16384: h fp32 -> fp8 e4m3 (x16), row-remapped, padded (fills the
//   CU tail; independent data, so free overlap). One dispatch fewer.
__global__ void prep_k(const float* __restrict__ W, u8* __restrict__ WT8,
                       const float* __restrict__ hs, u8* __restrict__ h8,
                       const int* __restrict__ boff,
                       const int* __restrict__ bent,
                       float* __restrict__ chlog) {
  __shared__ __align__(16) float t32[64][68];  // [d][v], row 272 B (16B-mult)
  __shared__ __align__(16) u8 t8[64][68];      // [d][v], u32-packed writes
  int bid = blockIdx.x;
  int tid = threadIdx.x;
  if (bid >= 16384) {                          // ---- conv_h role ----
    int idx = (bid - 16384) * 256 + tid;       // 1,048,576 threads
    int row = idx >> 8;
    int c8 = (idx & 255) << 3;
    u64 o = 0;
    if (row < NROWS) {
      int b = row / 1023, t = row % 1023;
      const float* p = hs + (size_t)((b << 10) + t) * DDIM + c8;
      float4 x = *(const float4*)p, y = *(const float4*)(p + 4);
      o = (u64)f2fp8(x.x * 16.f)        | ((u64)f2fp8(x.y * 16.f) << 8) |
          ((u64)f2fp8(x.z * 16.f) << 16) | ((u64)f2fp8(x.w * 16.f) << 24) |
          ((u64)f2fp8(y.x * 16.f) << 32) | ((u64)f2fp8(y.y * 16.f) << 40) |
          ((u64)f2fp8(y.z * 16.f) << 48) | ((u64)f2fp8(y.w * 16.f) << 56);
    }
    *(u64*)(h8 + (size_t)row * DDIM + c8) = o;
    return;
  }
  // ---- transpose_w role ----
  int vt = bid & 511, dt = bid >> 9;
  int v0 = vt << 6, d0 = dt << 6;
  int vi = (tid & 15) << 2, dl = tid >> 4;
#pragma unroll
  for (int i = 0; i < 4; ++i) {
    int d = dl + (i << 4);
    float4 w = *(const float4*)(W + (size_t)(d0 + d) * VDIM + v0 + vi);
    *(float4*)&t32[d][vi] = w;                  // 1x ds_write_b128
    unsigned p = (unsigned)f2fp8(w.x * 64.f) |
                 ((unsigned)f2fp8(w.y * 64.f) << 8) |
                 ((unsigned)f2fp8(w.z * 64.f) << 16) |
                 ((unsigned)f2fp8(w.w * 64.f) << 24);
    *(unsigned*)&t8[d][vi] = p;                 // 1x ds_write_b32
  }
  __syncthreads();
  // exact chosen dots first (atomics overlap with the output pass below)
  int m0 = boff[vt], m1 = boff[vt + 1];
  int lane = tid & 63, wv = tid >> 6;
  for (int m = m0 + wv; m < m1; m += 4) {
    int e = bent[m];
    int r = e >> 6, cv = e & 63;
    int b = r / 1023, tt = r % 1023;
    float s = hs[(size_t)((b << 10) + tt) * DDIM + d0 + lane] * t32[lane][cv];
#pragma unroll
    for (int o = 1; o < 64; o <<= 1) s += __shfl_xor(s, o, 64);
    if (lane == 0) atomicAdd(chlog + r, s);
  }
  // transposed fp8 write: 16 byte-reads (broadcast/2-way) + 16B global store
  int vr = tid >> 2, dc = (tid & 3) << 4;
  union { u8 b[16]; ulonglong2 q; } u;
#pragma unroll
  for (int k = 0; k < 16; ++k) u.b[k] = t8[dc + k][vr];
  *(ulonglong2*)(WT8 + (size_t)(v0 + vr) * DDIM + d0 + dc) = u.q;
}

// ---------- kernel 3: 256x256 fp8 GEMM, 128x64 wave tile, ni-outer loop ---
// (FROZEN: best measured 321 us, MfmaUtil 37.7%, 0 conflicts, no spill.)
__global__ __launch_bounds__(512, 2) void gemm_lse(
    const u8* __restrict__ A, const u8* __restrict__ Bt,
    float2* __restrict__ partials) {
  extern __shared__ u16 smem[];
  char* lds = (char*)smem;

  const int tid = threadIdx.x;
  const int l = tid & 63;
  const int wid = tid >> 6;                // 8 waves
  const int wm = wid >> 2, wn = wid & 3;   // 2 x 4
  const int ln = l & 15;
  const int g4 = l >> 4;
  const int xr = ln & 7;

  // XCD-bijective swizzle (2048 % 8 == 0)
  int bid = blockIdx.x;
  int id = ((bid & 7) << 8) | (bid >> 3);
  int bm = id & 15;                  // 0..15  (M tiles of 256)
  int bn = id >> 4;                  // 0..127 (N tiles of 256)
  const int m0 = bm << 8, n0 = bn << 8;

  const u8* Ab = A + (size_t)m0 * DDIM;
  const u8* Bb = Bt + (size_t)n0 * DDIM;

  // swizzled LDS read offsets: half u at slot ((u<<2)|g4) ^ xr, 16B units
  const unsigned aA0 = (unsigned)((wm << 14) + (ln << 7)) + (((0 | g4) ^ xr) << 4);
  const unsigned aA1 = (unsigned)((wm << 14) + (ln << 7)) + (((4 | g4) ^ xr) << 4);
  const unsigned aB0 = 32768u + (unsigned)((wn << 13) + (ln << 7)) + (((0 | g4) ^ xr) << 4);
  const unsigned aB1 = 32768u + (unsigned)((wn << 13) + (ln << 7)) + (((4 | g4) ^ xr) << 4);

  // staging: wave w stages segs {8j+w} j=0..3 (8 rows = 1 KB each) for A & B
  const int srow = l >> 3;
  const unsigned selb = (unsigned)(((l & 7) ^ srow) << 4);   // bytes
  unsigned voff[4];
#pragma unroll
  for (int j = 0; j < 4; ++j)
    voff[j] = (unsigned)(((((j << 3) + wid) << 3) | srow) * 2048) + selb;

#define RFL(x) __builtin_amdgcn_readfirstlane((int)(x))
#define GLL(src, dst) gload16((src), lds + RFL(dst))
#define LD4(off) (*(const i32x4*)(lds + (off)))
#define FRAG(b0, b1, o) SHUF(LD4((b0) + (o)), LD4((b1) + (o)))
#define DSTA(j) (unsigned)((((j) << 3) + wid) << 10)
#define DSTB(j) (32768u + (unsigned)((((j) << 3) + wid) << 10))

  f32x4 acc[8][4] = {};

  // prologue: tile0 (A+B) -> buf0; drain; barrier
#pragma unroll
  for (int j = 0; j < 4; ++j) GLL(Ab + voff[j], DSTA(j));
#pragma unroll
  for (int j = 0; j < 4; ++j) GLL(Bb + voff[j], DSTB(j));
  asm volatile("s_waitcnt vmcnt(0)" ::: "memory"); SB();
  BAR();
  SB();

  for (int t = 0; t < 16; ++t) {
    const unsigned fb = (unsigned)(t & 1) * BUFB;    // current buf
    const unsigned fbn = BUFB - fb;                  // next buf
    const u8* baseA = Ab + ((t + 1) << 7);           // A(t+1), uniform
    const u8* baseB = Bb + ((t + 1) << 7);           // B(t+1), uniform

    // FRONT-LOADED staging of tile t+1 (other buffer; no dependencies)
    if (t < 15) {
      GLL(baseA + voff[0], fbn + DSTA(0)); GLL(baseA + voff[1], fbn + DSTA(1));
      GLL(baseA + voff[2], fbn + DSTA(2)); GLL(baseA + voff[3], fbn + DSTA(3));
      GLL(baseB + voff[0], fbn + DSTB(0)); GLL(baseB + voff[1], fbn + DSTB(1));
      GLL(baseB + voff[2], fbn + DSTB(2)); GLL(baseB + voff[3], fbn + DSTB(3));
    }

    const unsigned rA0 = fb + aA0, rA1 = fb + aA1;
    const unsigned rB0 = fb + aB0, rB1 = fb + aB1;

    // A operands for the whole tile: af[8] = 64 regs (16 ds_read_b128)
    i32x8 af[8];
#pragma unroll
    for (int mi = 0; mi < 8; ++mi) af[mi] = FRAG(rA0, rA1, mi * 2048);

#pragma unroll
    for (int ni = 0; ni < 4; ++ni) {
      i32x8 bf = FRAG(rB0, rB1, ni * 2048);
#pragma unroll
      for (int mi = 0; mi < 8; ++mi)
        acc[mi][ni] = __builtin_amdgcn_mfma_scale_f32_16x16x128_f8f6f4(
            af[mi], bf, acc[mi][ni], 0, 0, 0, SC8, 0, SC8);
    }
    if (t < 15) { asm volatile("s_waitcnt vmcnt(0)" ::: "memory"); }
    SB();
    BAR();   // boundary: tile t+1 fully landed, flip buffer
    SB();
  }

  // epilogue: per-row (max, sum-exp) over the wave's 64 cols (scale /1024)
  // C/D layout: col = lane&15, row = (lane>>4)*4 + reg
  const int chunk = (bn << 2) | wn;
#pragma unroll
  for (int mi = 0; mi < 8; ++mi) {
#pragma unroll
    for (int rr = 0; rr < 4; ++rr) {
      const int row = m0 + (wm << 7) + (mi << 4) + (g4 << 2) + rr;
      float v0 = acc[mi][0][rr] * 0.0009765625f;
      float v1 = acc[mi][1][rr] * 0.0009765625f;
      float v2 = acc[mi][2][rr] * 0.0009765625f;
      float v3 = acc[mi][3][rr] * 0.0009765625f;
      float mx = fmaxf(fmaxf(v0, v1), fmaxf(v2, v3));
#pragma unroll
      for (int o = 1; o < 16; o <<= 1) mx = fmaxf(mx, __shfl_xor(mx, o, 64));
      float s = __expf(v0 - mx) + __expf(v1 - mx) + __expf(v2 - mx) + __expf(v3 - mx);
#pragma unroll
      for (int o = 1; o < 16; o <<= 1) s += __shfl_xor(s, o, 64);
      if (ln == 0) partials[(size_t)row * NCHUNK + chunk] = make_float2(mx, s);
    }
  }
#undef DSTA
#undef DSTB
#undef FRAG
#undef LD4
#undef GLL
#undef RFL
}

// ---------- kernel 4: combine partials -> lse -> logps -> loss terms ------
__global__ void reduce_lse(const float2* __restrict__ partials,
                           const float* __restrict__ chlog,
                           const float* __restrict__ oldlp,
                           const int* __restrict__ labels,
                           const float* __restrict__ adv,
                           float* __restrict__ out, float* __restrict__ accum) {
  const int wid = threadIdx.x >> 6, l = threadIdx.x & 63;
  const int row = blockIdx.x * 4 + wid;        // 1023*4 = 4092 exactly
  float M = -INFINITY, S = 0.f;
  for (int c = l; c < NCHUNK; c += 64) {
    float2 p = partials[(size_t)row * NCHUNK + c];
    float Mn = fmaxf(M, p.x);
    S = S * __expf(M - Mn) + p.y * __expf(p.x - Mn);
    M = Mn;
  }
#pragma unroll
  for (int o = 1; o < 64; o <<= 1) {
    float Mo = __shfl_xor(M, o, 64), So = __shfl_xor(S, o, 64);
    float Mn = fmaxf(M, Mo);
    S = S * __expf(M - Mn) + So * __expf(Mo - Mn);
    M = Mn;
  }
  if (l == 0) {
    float lse = M + __logf(S);
    float ptl = chlog[row] - lse;
    out[1 + row] = ptl;
    int b = row / 1023, t = row % 1023;
    float a = adv[b];
    float ratio = __expf(ptl - oldlp[row]);
    float l1 = ratio * a;
    float l2 = fminf(fmaxf(ratio, 0.8f), 1.3f) * a;
    float mk = (float)labels[b * 1024 + t + 1];
    atomicAdd(accum + 0, -fminf(l1, l2) * mk);
    atomicAdd(accum + 1, mk);
  }
}

__global__ void finalize_k(const float* __restrict__ accum, float* __restrict__ out) {
  out[0] = accum[0] / accum[1];
}

// ---------- launch ----------
extern "C" void kernel_launch(void* const* d_in, const int* in_sizes, int n_in,
                              void* d_out, int out_size, void* d_ws, size_t ws_size,
                              hipStream_t stream) {
  const float* hs     = (const float*)d_in[0];   // (4,1024,2048)
  const float* W      = (const float*)d_in[1];   // (2048,32768)
  const int*   ids    = (const int*)d_in[2];     // (4,1024)
  const int*   labels = (const int*)d_in[3];     // (4,1024)
  const float* adv    = (const float*)d_in[4];   // (4,)
  const float* oldlp  = (const float*)d_in[5];   // (4,1023)
  float* out = (float*)d_out;                    // [loss, 4092 x per_token_logps]

  // ws layout (~92.4 MB)
  char* ws = (char*)d_ws;
  u8*     WT8      = (u8*)ws;                          //  67,108,864 B
  u8*     h8       = (u8*)(ws + 67108864);             //   8,388,608 B
  float2* partials = (float2*)(ws + 75497472);         //  16,777,216 B
  float*  chlog    = (float*)(ws + 92274688);          //      16,384 B
  float*  accum    = (float*)(ws + 92291072);          //          64 B (pad)
  int*    boff     = (int*)(ws + 92291136);            //       2,112 B (513+pad)
  int*    bent     = (int*)(ws + 92293248);            //      16,384 B

  (void)hipFuncSetAttribute((const void*)gemm_lse,
                            hipFuncAttributeMaxDynamicSharedMemorySize, 131072);

  bucket_k<<<1, 512, 0, stream>>>(ids, boff, bent, chlog, accum);
  prep_k<<<20480, 256, 0, stream>>>(W, WT8, hs, h8, boff, bent, chlog);
  gemm_lse<<<2048, 512, 131072, stream>>>(h8, WT8, partials);
  reduce_lse<<<1023, 256, 0, stream>>>(partials, chlog, oldlp, labels, adv, out, accum);
  finalize_k<<<1, 1, 0, stream>>>(accum, out);
}